// Round 8
// baseline (158.704 us; speedup 1.0000x reference)
//
#include <hip/hip_runtime.h>
#include <stdint.h>

typedef __attribute__((ext_vector_type(4))) float f32x4;
typedef __attribute__((ext_vector_type(8))) __bf16 bf16x8;

#define MFMA16(a, b, c) __builtin_amdgcn_mfma_f32_16x16x32_bf16(a, b, c, 0, 0, 0)
#define GLOAD16(g, l)                                                              \
  __builtin_amdgcn_global_load_lds(                                                \
      (const __attribute__((address_space(1))) unsigned int*)(g),                  \
      (__attribute__((address_space(3))) unsigned int*)(l), 16, 0, 0)
#define EXP2F(x) __builtin_amdgcn_exp2f(x)

static __device__ __forceinline__ unsigned short f2b(float f) {
  unsigned int u = __float_as_uint(f);
  u += 0x7fff + ((u >> 16) & 1);
  return (unsigned short)(u >> 16);
}
static __device__ __forceinline__ float b2f(unsigned short h) {
  unsigned int u = ((unsigned int)h) << 16;
  return __uint_as_float(u);
}

#define NROWS 8192
#define DIN   1024
#define DH    128
#define DOUT  1024

// ---------------------------------------------------------------- k1: weights -> bf16, transposed (LDS-tiled)
__global__ void k_convert_w(const float* __restrict__ wqkv, const float* __restrict__ wout,
                            unsigned short* __restrict__ wqkvT, unsigned short* __restrict__ woutT) {
  __shared__ float t[64][65];
  const int bid = blockIdx.x;
  const float* src;
  unsigned short* dst;
  int k0, n0, sstride, dstride;
  if (bid < 96) {                       // wqkv [1024][384] -> wqkvT [384][1024]
    int kt = bid / 6, nt = bid % 6;
    k0 = kt * 64; n0 = nt * 64;
    src = wqkv; sstride = 384; dst = wqkvT; dstride = 1024;
  } else {                              // wout [128][1024] -> woutT [1024][128]
    int b2 = bid - 96;
    int kt = b2 & 1, nt = b2 >> 1;
    k0 = kt * 64; n0 = nt * 64;
    src = wout; sstride = 1024; dst = woutT; dstride = 128;
  }
  const int tid = threadIdx.x;
  const int r = tid >> 4, c4 = (tid & 15) * 4;
#pragma unroll
  for (int j = 0; j < 4; ++j) {
    int rr = r + j * 16;
    float4 v = *reinterpret_cast<const float4*>(src + (size_t)(k0 + rr) * sstride + n0 + c4);
    t[rr][c4 + 0] = v.x; t[rr][c4 + 1] = v.y; t[rr][c4 + 2] = v.z; t[rr][c4 + 3] = v.w;
  }
  __syncthreads();
#pragma unroll
  for (int j = 0; j < 4; ++j) {
    int rn = r + j * 16;
    ushort4 h;
    h.x = f2b(t[c4 + 0][rn]); h.y = f2b(t[c4 + 1][rn]);
    h.z = f2b(t[c4 + 2][rn]); h.w = f2b(t[c4 + 3][rn]);
    *reinterpret_cast<ushort4*>(dst + (size_t)(n0 + rn) * dstride + k0 + c4) = h;
  }
}

// ---------------------------------------------------------------- k1b: x -> bf16
__global__ void k_convert_x(const float* __restrict__ x, unsigned short* __restrict__ xb) {
  int i = (blockIdx.x * 256 + threadIdx.x) * 4;
  float4 v = *reinterpret_cast<const float4*>(x + i);
  ushort4 h;
  h.x = f2b(v.x); h.y = f2b(v.y); h.z = f2b(v.z); h.w = f2b(v.w);
  *reinterpret_cast<ushort4*>(xb + i) = h;
}

// ---------------------------------------------------------------- k2: qkv GEMM, 128x128 tile, dbuf, XCD remap
__launch_bounds__(256, 2)
__global__ void k_qkv_gemm(const unsigned short* __restrict__ xb, const unsigned short* __restrict__ wT,
                           const float* __restrict__ bqkv,
                           unsigned short* __restrict__ Qb, unsigned short* __restrict__ Kb,
                           unsigned short* __restrict__ Vb) {
  const int hb = blockIdx.x;              // 0..191
  const int xcd = hb & 7, jj = hb >> 3;
  const int tau = xcd * 24 + jj;
  const int bn = tau % 3, bm = tau / 3;
  const int tid = threadIdx.x;
  const int lane = tid & 63, w = tid >> 6;
  const int l15 = lane & 15, g = lane >> 4;
  const int wm = (w >> 1) * 64, wn = (w & 1) * 64;
  const int row0 = bm * 128, col0 = bn * 128;

  __shared__ __align__(16) char Ash[2][16384];   // [128][64] bf16, swz
  __shared__ __align__(16) char Bsh[2][16384];

  f32x4 acc[4][4] = {};

#define QKV_STAGE(k0, buf)                                                          \
  {                                                                                 \
    _Pragma("unroll")                                                               \
    for (int j2 = 0; j2 < 4; ++j2) {                                                \
      int idx = j2 * 256 + tid;                                                     \
      int r = idx >> 3, gg = idx & 7, sgg = gg ^ (r & 7);                           \
      GLOAD16(xb + (size_t)(row0 + r) * DIN + (k0) + sgg * 8, Ash[buf] + idx * 16); \
      GLOAD16(wT + (size_t)(col0 + r) * DIN + (k0) + sgg * 8, Bsh[buf] + idx * 16); \
    }                                                                               \
  }

  QKV_STAGE(0, 0);
  __syncthreads();
  int cur = 0;
  for (int k0 = 0; k0 < DIN; k0 += 64) {
    if (k0 + 64 < DIN) QKV_STAGE(k0 + 64, cur ^ 1);
#pragma unroll
    for (int ksl = 0; ksl < 2; ++ksl) {
      bf16x8 af[4], bfr[4];
#pragma unroll
      for (int i = 0; i < 4; ++i) {
        int r = wm + i * 16 + l15;
        int ba = r * 128 + ksl * 64 + g * 16;
        af[i] = *reinterpret_cast<bf16x8*>(Ash[cur] + (ba ^ ((r & 7) << 4)));
        int n = wn + i * 16 + l15;
        int bb = n * 128 + ksl * 64 + g * 16;
        bfr[i] = *reinterpret_cast<bf16x8*>(Bsh[cur] + (bb ^ ((n & 7) << 4)));
      }
#pragma unroll
      for (int i = 0; i < 4; ++i)
#pragma unroll
        for (int jn = 0; jn < 4; ++jn)
          acc[i][jn] = MFMA16(af[i], bfr[jn], acc[i][jn]);
    }
    __syncthreads();
    cur ^= 1;
  }

  unsigned short* outb = (bn == 0) ? Qb : (bn == 1 ? Kb : Vb);
#pragma unroll
  for (int i = 0; i < 4; ++i)
#pragma unroll
    for (int jn = 0; jn < 4; ++jn)
#pragma unroll
      for (int r = 0; r < 4; ++r) {
        int grow = row0 + wm + i * 16 + g * 4 + r;
        int lcol = wn + jn * 16 + l15;
        float vv = acc[i][jn][r] + bqkv[bn * 128 + lcol];
        outb[(size_t)grow * DH + lcol] = f2b(vv);
      }
}

// ---------------------------------------------------------------- k3: V [8192][128] -> V^T [128][8192]
__global__ void k_transpose_v(const unsigned short* __restrict__ V, unsigned short* __restrict__ VT) {
  __shared__ __align__(16) unsigned short t[64 * 128];
  const int b = blockIdx.x;
  const int tid = threadIdx.x;
  const int kv0 = b * 64;
#pragma unroll
  for (int j = 0; j < 4; ++j) {
    int c = j * 256 + tid;
    int r = c >> 4, cc = (c & 15) * 8;
    uint4 v = *reinterpret_cast<const uint4*>(V + (size_t)(kv0 + r) * DH + cc);
    int col = (cc + ((r >> 3) & 7) * 8) & 127;
    *reinterpret_cast<uint4*>(&t[r * 128 + col]) = v;
  }
  __syncthreads();
#pragma unroll
  for (int j = 0; j < 4; ++j) {
    int c = j * 256 + tid;
    int d = c >> 3, kk = (c & 7) * 8;
    unsigned short tmp[8];
#pragma unroll
    for (int e = 0; e < 8; ++e) {
      int r = kk + e;
      int col = (d + ((r >> 3) & 7) * 8) & 127;
      tmp[e] = t[r * 128 + col];
    }
    *reinterpret_cast<uint4*>(VT + (size_t)d * NROWS + kv0 + kk) = *reinterpret_cast<uint4*>(tmp);
  }
}

// ---------------------------------------------------------------- k4: causal flash, 4 waves x 32q (2 subtiles)
// Swapped MFMA (S^T/O^T), per-lane softmax. Single-buffer K/V (48KB LDS -> 3 blocks/CU) with
// T14 reg-staging: global->reg at step start (latency hides under compute), reg->LDS after barrier.
// launch_bounds(256,2): never raise min-waves (r3/r5: allocator drops a VGPR tier and spills).
__launch_bounds__(256, 2)
__global__ void k_flash(const unsigned short* __restrict__ Q, const unsigned short* __restrict__ Kg,
                        const unsigned short* __restrict__ VT,
                        unsigned short* __restrict__ Opart, float* __restrict__ MLpart, int LQ) {
  const int ci = blockIdx.x;
  const int t = (int)(gridDim.y - 1) - (int)blockIdx.y;   // heavy tiles first
  const int Jq = 1 << LQ;                                 // chunk = Jq*128 kv
  if (ci * Jq > t) return;
  const int qb = t << 7;
  const int ks = ci * (Jq << 7);
  const int ke = min(ks + (Jq << 7), qb + 128);
  const int nsteps = (ke - ks) >> 6;

  const int a = t >> LQ, b = t & (Jq - 1);
  const int slot = t + ((Jq * a * (a - 1)) >> 1) + a * b + ci;

  const int tid = threadIdx.x;
  const int lane = tid & 63, w = tid >> 6;
  const int l15 = lane & 15, g = lane >> 4;

  __shared__ __align__(16) char Ksh[16384];      // K [64][128] bf16, swz
  __shared__ __align__(16) char Vsh[16384];      // V^T [128][64] bf16, swz
  __shared__ __align__(16) char Psh[4][4096];    // per-wave P [32 q][64 k] bf16, swz

  const int qr0 = qb + w * 16 + l15;             // subtile-0 q row
  const int qr1 = qr0 + 64;                      // subtile-1 q row
  bf16x8 qf0[4], qf1[4];
#pragma unroll
  for (int d = 0; d < 4; ++d) {
    qf0[d] = *reinterpret_cast<const bf16x8*>(Q + (size_t)qr0 * DH + d * 32 + g * 8);
    qf1[d] = *reinterpret_cast<const bf16x8*>(Q + (size_t)qr1 * DH + d * 32 + g * 8);
  }

  f32x4 acco0[8] = {}, acco1[8] = {};
  float m0 = -1e30f, l0 = 0.f, m1 = -1e30f, l1 = 0.f;
  const float c2 = 0.08838834764831843f * 1.4426950408889634f;   // scale * log2(e)

  char* Pw = Psh[w];

  // prologue stage (direct global->LDS)
#pragma unroll
  for (int j2 = 0; j2 < 4; ++j2) {
    int idx = j2 * 256 + tid;
    int r = idx >> 4, gg = idx & 15, sgg = gg ^ (r & 7);
    GLOAD16(Kg + (size_t)(ks + r) * DH + sgg * 8, Ksh + idx * 16);
  }
#pragma unroll
  for (int j2 = 0; j2 < 4; ++j2) {
    int idx = j2 * 256 + tid;
    int d = idx >> 3, gg = idx & 7, sgg = gg ^ (d & 7);
    GLOAD16(VT + (size_t)d * NROWS + ks + sgg * 8, Vsh + idx * 16);
  }
  __syncthreads();

  for (int s = 0; s < nsteps; ++s) {
    const int kv0 = ks + (s << 6);
    const bool pre = (s + 1 < nsteps);

    // T14 reg-stage for next tile: issue early, write after the read-barrier
    uint4 kreg[4], vreg[4];
    if (pre) {
      const int kv1 = kv0 + 64;
#pragma unroll
      for (int j2 = 0; j2 < 4; ++j2) {
        int idx = j2 * 256 + tid;
        int r = idx >> 4, gg = idx & 15, sgg = gg ^ (r & 7);
        kreg[j2] = *reinterpret_cast<const uint4*>(Kg + (size_t)(kv1 + r) * DH + sgg * 8);
      }
#pragma unroll
      for (int j2 = 0; j2 < 4; ++j2) {
        int idx = j2 * 256 + tid;
        int d = idx >> 3, gg = idx & 7, sgg = gg ^ (d & 7);
        vreg[j2] = *reinterpret_cast<const uint4*>(VT + (size_t)d * NROWS + kv1 + sgg * 8);
      }
    }

    // subtile-0 fully masked iff kv0 >= qb+64 (block-uniform, only final diagonal step)
    const bool act0 = (kv0 < qb + 64);

    // QK^T (S^T): each K fragment read once, feeds both subtiles
    f32x4 accs0[4] = {}, accs1[4] = {};
    if (act0) {
#pragma unroll
      for (int jc = 0; jc < 4; ++jc)
#pragma unroll
        for (int d = 0; d < 4; ++d) {
          int r = jc * 16 + l15;
          int byte = r * 256 + d * 64 + g * 16; byte ^= (r & 7) << 4;
          bf16x8 kf = *reinterpret_cast<bf16x8*>(Ksh + byte);
          accs1[jc] = MFMA16(kf, qf1[d], accs1[jc]);
          accs0[jc] = MFMA16(kf, qf0[d], accs0[jc]);
        }
    } else {
#pragma unroll
      for (int jc = 0; jc < 4; ++jc)
#pragma unroll
        for (int d = 0; d < 4; ++d) {
          int r = jc * 16 + l15;
          int byte = r * 256 + d * 64 + g * 16; byte ^= (r & 7) << 4;
          bf16x8 kf = *reinterpret_cast<bf16x8*>(Ksh + byte);
          accs1[jc] = MFMA16(kf, qf1[d], accs1[jc]);
        }
    }

#define SOFTMAX_PW(ACCS, ACCO, M, L, QROW, ROWBASE)                                   \
    {                                                                                 \
      float p[4][4];                                                                  \
      float mx = -3e38f;                                                              \
      _Pragma("unroll")                                                               \
      for (int jc = 0; jc < 4; ++jc)                                                  \
        _Pragma("unroll")                                                             \
        for (int r = 0; r < 4; ++r) {                                                 \
          float sv = ACCS[jc][r] * c2;                                                \
          int kk = kv0 + jc * 16 + (g << 2) + r;                                      \
          sv = (kk <= (QROW)) ? sv : -3e38f;                                          \
          p[jc][r] = sv;                                                              \
          mx = fmaxf(mx, sv);                                                         \
        }                                                                             \
      mx = fmaxf(mx, __shfl_xor(mx, 16));                                             \
      mx = fmaxf(mx, __shfl_xor(mx, 32));                                             \
      float mnew = fmaxf(M, mx);                                                      \
      float fac = EXP2F(M - mnew);                                                    \
      float ps = 0.f;                                                                 \
      _Pragma("unroll")                                                               \
      for (int jc = 0; jc < 4; ++jc)                                                  \
        _Pragma("unroll")                                                             \
        for (int r = 0; r < 4; ++r) {                                                 \
          float e = EXP2F(p[jc][r] - mnew);                                           \
          p[jc][r] = e; ps += e;                                                      \
        }                                                                             \
      ps += __shfl_xor(ps, 16);                                                       \
      ps += __shfl_xor(ps, 32);                                                       \
      L = L * fac + ps;                                                               \
      M = mnew;                                                                       \
      _Pragma("unroll")                                                               \
      for (int dc = 0; dc < 8; ++dc)                                                  \
        _Pragma("unroll")                                                             \
        for (int r = 0; r < 4; ++r) ACCO[dc][r] *= fac;                               \
      int rq = (ROWBASE) + l15;                                                       \
      _Pragma("unroll")                                                               \
      for (int jc = 0; jc < 4; ++jc) {                                                \
        ushort4 pb;                                                                   \
        pb.x = f2b(p[jc][0]); pb.y = f2b(p[jc][1]);                                   \
        pb.z = f2b(p[jc][2]); pb.w = f2b(p[jc][3]);                                   \
        int byte = rq * 128 + jc * 32 + g * 8; byte ^= (rq & 7) << 4;                 \
        *reinterpret_cast<ushort4*>(Pw + byte) = pb;                                  \
      }                                                                               \
    }

    if (act0) SOFTMAX_PW(accs0, acco0, m0, l0, qr0, 0);
    SOFTMAX_PW(accs1, acco1, m1, l1, qr1, 16);
    __asm__ volatile("s_waitcnt lgkmcnt(0)" ::: "memory");
    __builtin_amdgcn_sched_barrier(0);

    // PV (O^T): each V fragment read once, feeds both subtiles
    bf16x8 pf1[2];
#pragma unroll
    for (int ks2 = 0; ks2 < 2; ++ks2) {
      int rq = 16 + l15;
      int byte = rq * 128 + ks2 * 64 + g * 16; byte ^= (rq & 7) << 4;
      pf1[ks2] = *reinterpret_cast<bf16x8*>(Pw + byte);
    }
    if (act0) {
      bf16x8 pf0[2];
#pragma unroll
      for (int ks2 = 0; ks2 < 2; ++ks2) {
        int byte = l15 * 128 + ks2 * 64 + g * 16; byte ^= (l15 & 7) << 4;
        pf0[ks2] = *reinterpret_cast<bf16x8*>(Pw + byte);
      }
#pragma unroll
      for (int dc = 0; dc < 8; ++dc) {
        int vr = dc * 16 + l15;
        int b0 = vr * 128 + g * 16; b0 ^= (vr & 7) << 4;
        bf16x8 vf0 = *reinterpret_cast<bf16x8*>(Vsh + b0);
        bf16x8 vf1 = *reinterpret_cast<bf16x8*>(Vsh + (b0 ^ 64));
        acco1[dc] = MFMA16(vf0, pf1[0], acco1[dc]);
        acco1[dc] = MFMA16(vf1, pf1[1], acco1[dc]);
        acco0[dc] = MFMA16(vf0, pf0[0], acco0[dc]);
        acco0[dc] = MFMA16(vf1, pf0[1], acco0[dc]);
      }
    } else {
#pragma unroll
      for (int dc = 0; dc < 8; ++dc) {
        int vr = dc * 16 + l15;
        int b0 = vr * 128 + g * 16; b0 ^= (vr & 7) << 4;
        bf16x8 vf0 = *reinterpret_cast<bf16x8*>(Vsh + b0);
        bf16x8 vf1 = *reinterpret_cast<bf16x8*>(Vsh + (b0 ^ 64));
        acco1[dc] = MFMA16(vf0, pf1[0], acco1[dc]);
        acco1[dc] = MFMA16(vf1, pf1[1], acco1[dc]);
      }
    }

    __syncthreads();                 // all waves done reading Ksh/Vsh
    if (pre) {
#pragma unroll
      for (int j2 = 0; j2 < 4; ++j2) {
        int idx = j2 * 256 + tid;
        *reinterpret_cast<uint4*>(Ksh + idx * 16) = kreg[j2];
        *reinterpret_cast<uint4*>(Vsh + idx * 16) = vreg[j2];
      }
      __syncthreads();               // new tile visible to all waves
    }
  }

  // epilogue: bf16 partials; lane holds O[q][d = dc*16 + g*4 + r]
  const size_t r0 = (size_t)slot * 128 + w * 16 + l15;
  const size_t r1 = r0 + 64;
#pragma unroll
  for (int dc = 0; dc < 8; ++dc) {
    ushort4 o0, o1;
    o0.x = f2b(acco0[dc][0]); o0.y = f2b(acco0[dc][1]);
    o0.z = f2b(acco0[dc][2]); o0.w = f2b(acco0[dc][3]);
    o1.x = f2b(acco1[dc][0]); o1.y = f2b(acco1[dc][1]);
    o1.z = f2b(acco1[dc][2]); o1.w = f2b(acco1[dc][3]);
    *reinterpret_cast<ushort4*>(Opart + r0 * DH + dc * 16 + (g << 2)) = o0;
    *reinterpret_cast<ushort4*>(Opart + r1 * DH + dc * 16 + (g << 2)) = o1;
  }
  if (g == 0) {
    MLpart[r0 * 2 + 0] = m0;
    MLpart[r0 * 2 + 1] = l0;
    MLpart[r1 * 2 + 0] = m1;
    MLpart[r1 * 2 + 1] = l1;
  }
}

// ---------------------------------------------------------------- k5: merge chunk partials (bf16) -> O bf16
__global__ void k_merge(const unsigned short* __restrict__ Opart, const float* __restrict__ MLpart,
                        unsigned short* __restrict__ O, int LQ) {
  int tg = blockIdx.x * 256 + threadIdx.x;     // over 8192*32
  int row = tg >> 5, d4 = (tg & 31) * 4;
  int t = row >> 7;                            // 128-row q tiles
  int Jq = 1 << LQ;
  int a = t >> LQ, b = t & (Jq - 1);
  int base = t + ((Jq * a * (a - 1)) >> 1) + a * b;
  int nc = a + 1;
  int rowin = row & 127;
  float M = -3e38f;
  for (int i = 0; i < nc; ++i) M = fmaxf(M, MLpart[((size_t)(base + i) * 128 + rowin) * 2]);
  float L = 0.f;
  f32x4 acc = {};
  for (int i = 0; i < nc; ++i) {
    size_t sr = (size_t)(base + i) * 128 + rowin;
    float mi = MLpart[sr * 2];
    float li = MLpart[sr * 2 + 1];
    float wg = EXP2F(mi - M);
    L += li * wg;
    ushort4 o = *reinterpret_cast<const ushort4*>(Opart + sr * DH + d4);
    acc[0] += wg * b2f(o.x); acc[1] += wg * b2f(o.y);
    acc[2] += wg * b2f(o.z); acc[3] += wg * b2f(o.w);
  }
  float inv = 1.f / L;
  ushort4 hv;
  hv.x = f2b(acc[0] * inv); hv.y = f2b(acc[1] * inv);
  hv.z = f2b(acc[2] * inv); hv.w = f2b(acc[3] * inv);
  *reinterpret_cast<ushort4*>(O + (size_t)row * DH + d4) = hv;
}

// ---------------------------------------------------------------- k6: out GEMM, XCD remap
__launch_bounds__(256, 2)
__global__ void k_out_gemm(const unsigned short* __restrict__ O, const unsigned short* __restrict__ wT,
                           const float* __restrict__ bout, float* __restrict__ out) {
  const int hb = blockIdx.x;               // 0..2047
  const int xcd = hb & 7, jj = hb >> 3;
  const int tau = xcd * 256 + jj;
  const int bn = tau & 15, bm = tau >> 4;
  const int tid = threadIdx.x;
  const int lane = tid & 63, w = tid >> 6;
  const int l15 = lane & 15, g = lane >> 4;
  const int wm = (w >> 1) * 32, wn = (w & 1) * 32;
  const int row0 = bm * 64, col0 = bn * 64;

  __shared__ __align__(16) char Ash[16384];
  __shared__ __align__(16) char Bsh[16384];

#pragma unroll
  for (int j = 0; j < 4; ++j) {
    int idx = j * 256 + tid;
    int r = idx >> 4, gg = idx & 15;
    int sgg = gg ^ (r & 7);
    GLOAD16(O + (size_t)(row0 + r) * DH + sgg * 8, Ash + idx * 16);
    GLOAD16(wT + (size_t)(col0 + r) * DH + sgg * 8, Bsh + idx * 16);
  }
  __syncthreads();

  f32x4 acc[2][2] = {};
#pragma unroll
  for (int ksl = 0; ksl < 4; ++ksl) {
    bf16x8 af[2], bfr[2];
#pragma unroll
    for (int i = 0; i < 2; ++i) {
      int r = wm + i * 16 + l15;
      int ba = r * 256 + ksl * 64 + g * 16;
      af[i] = *reinterpret_cast<bf16x8*>(Ash + (ba ^ ((r & 7) << 4)));
      int n = wn + i * 16 + l15;
      int bb = n * 256 + ksl * 64 + g * 16;
      bfr[i] = *reinterpret_cast<bf16x8*>(Bsh + (bb ^ ((n & 7) << 4)));
    }
#pragma unroll
    for (int i = 0; i < 2; ++i)
#pragma unroll
      for (int jn = 0; jn < 2; ++jn)
        acc[i][jn] = MFMA16(af[i], bfr[jn], acc[i][jn]);
  }

#pragma unroll
  for (int i = 0; i < 2; ++i)
#pragma unroll
    for (int jn = 0; jn < 2; ++jn)
#pragma unroll
      for (int r = 0; r < 4; ++r) {
        int grow = row0 + wm + i * 16 + g * 4 + r;
        int gcol = col0 + wn + jn * 16 + l15;
        out[(size_t)grow * DOUT + gcol] = acc[i][jn][r] + bout[gcol];
      }
}

// ---------------------------------------------------------------- launch
extern "C" void kernel_launch(void* const* d_in, const int* in_sizes, int n_in,
                              void* d_out, int out_size, void* d_ws, size_t ws_size,
                              hipStream_t stream) {
  const float* x    = (const float*)d_in[0];
  const float* wqkv = (const float*)d_in[1];
  const float* bqkv = (const float*)d_in[2];
  const float* wout = (const float*)d_in[3];
  const float* bout = (const float*)d_in[4];
  float* out = (float*)d_out;

  // adaptive KV-chunk: 64 q-tiles of 128 rows; chunk = Jq*128 kv. Smallest Jq that fits ws.
  // Opart is bf16 now (2 B/elem), enabling LQ=1 (1056 blocks) in the same workspace.
  size_t fixed = 786432 + 262144 + (size_t)NROWS * DIN * 2 + (size_t)5 * NROWS * DH * 2;
  int LQ = 1;
  size_t slots = 0;
  for (; LQ <= 6; ++LQ) {
    int Jq = 1 << LQ, A = 64 / Jq;
    slots = (size_t)Jq * A * (A + 1) / 2;
    size_t need = fixed + slots * ((size_t)128 * DH * 2 + 128 * 8);
    if (need <= ws_size || LQ == 6) break;
  }

  char* ws = (char*)d_ws;
  size_t off = 0;
  unsigned short* wqkvT = (unsigned short*)(ws + off); off += (size_t)384 * 1024 * 2;
  unsigned short* woutT = (unsigned short*)(ws + off); off += (size_t)1024 * 128 * 2;
  unsigned short* xb  = (unsigned short*)(ws + off); off += (size_t)NROWS * DIN * 2;
  unsigned short* Qb  = (unsigned short*)(ws + off); off += (size_t)NROWS * DH * 2;
  unsigned short* Kb  = (unsigned short*)(ws + off); off += (size_t)NROWS * DH * 2;
  unsigned short* Vb  = (unsigned short*)(ws + off); off += (size_t)NROWS * DH * 2;
  unsigned short* VTb = (unsigned short*)(ws + off); off += (size_t)NROWS * DH * 2;
  unsigned short* Ob  = (unsigned short*)(ws + off); off += (size_t)NROWS * DH * 2;
  unsigned short* Opart = (unsigned short*)(ws + off); off += slots * (size_t)128 * DH * 2;
  float* MLpart = (float*)(ws + off); off += slots * (size_t)128 * 8;

  k_convert_w<<<128, 256, 0, stream>>>(wqkv, wout, wqkvT, woutT);
  k_convert_x<<<(NROWS * DIN) / 1024, 256, 0, stream>>>(x, xb);
  k_qkv_gemm<<<192, 256, 0, stream>>>(xb, wqkvT, bqkv, Qb, Kb, Vb);
  k_transpose_v<<<128, 256, 0, stream>>>(Vb, VTb);
  k_flash<<<dim3(64 >> LQ, 64), 256, 0, stream>>>(Qb, Kb, VTb, Opart, MLpart, LQ);
  k_merge<<<(NROWS * 32) / 256, 256, 0, stream>>>(Opart, MLpart, Ob, LQ);
  k_out_gemm<<<2048, 256, 0, stream>>>(Ob, woutT, bout, out);
}

// Round 9
// 115.515 us; speedup vs baseline: 1.3739x; 1.3739x over previous
//
#include <hip/hip_runtime.h>
#include <stdint.h>

typedef __attribute__((ext_vector_type(4))) float f32x4;
typedef __attribute__((ext_vector_type(8))) __bf16 bf16x8;

#define MFMA16(a, b, c) __builtin_amdgcn_mfma_f32_16x16x32_bf16(a, b, c, 0, 0, 0)
#define GLOAD16(g, l)                                                              \
  __builtin_amdgcn_global_load_lds(                                                \
      (const __attribute__((address_space(1))) unsigned int*)(g),                  \
      (__attribute__((address_space(3))) unsigned int*)(l), 16, 0, 0)
#define EXP2F(x) __builtin_amdgcn_exp2f(x)

static __device__ __forceinline__ unsigned short f2b(float f) {
  unsigned int u = __float_as_uint(f);
  u += 0x7fff + ((u >> 16) & 1);
  return (unsigned short)(u >> 16);
}
static __device__ __forceinline__ float b2f(unsigned short h) {
  unsigned int u = ((unsigned int)h) << 16;
  return __uint_as_float(u);
}

#define NROWS 8192
#define DIN   1024
#define DH    128
#define DOUT  1024

// ---------------------------------------------------------------- k1: weights -> bf16, transposed (LDS-tiled)
__global__ void k_convert_w(const float* __restrict__ wqkv, const float* __restrict__ wout,
                            unsigned short* __restrict__ wqkvT, unsigned short* __restrict__ woutT) {
  __shared__ float t[64][65];
  const int bid = blockIdx.x;
  const float* src;
  unsigned short* dst;
  int k0, n0, sstride, dstride;
  if (bid < 96) {                       // wqkv [1024][384] -> wqkvT [384][1024]
    int kt = bid / 6, nt = bid % 6;
    k0 = kt * 64; n0 = nt * 64;
    src = wqkv; sstride = 384; dst = wqkvT; dstride = 1024;
  } else {                              // wout [128][1024] -> woutT [1024][128]
    int b2 = bid - 96;
    int kt = b2 & 1, nt = b2 >> 1;
    k0 = kt * 64; n0 = nt * 64;
    src = wout; sstride = 1024; dst = woutT; dstride = 128;
  }
  const int tid = threadIdx.x;
  const int r = tid >> 4, c4 = (tid & 15) * 4;
#pragma unroll
  for (int j = 0; j < 4; ++j) {
    int rr = r + j * 16;
    float4 v = *reinterpret_cast<const float4*>(src + (size_t)(k0 + rr) * sstride + n0 + c4);
    t[rr][c4 + 0] = v.x; t[rr][c4 + 1] = v.y; t[rr][c4 + 2] = v.z; t[rr][c4 + 3] = v.w;
  }
  __syncthreads();
#pragma unroll
  for (int j = 0; j < 4; ++j) {
    int rn = r + j * 16;
    ushort4 h;
    h.x = f2b(t[c4 + 0][rn]); h.y = f2b(t[c4 + 1][rn]);
    h.z = f2b(t[c4 + 2][rn]); h.w = f2b(t[c4 + 3][rn]);
    *reinterpret_cast<ushort4*>(dst + (size_t)(n0 + rn) * dstride + k0 + c4) = h;
  }
}

// ---------------------------------------------------------------- k1b: x -> bf16
__global__ void k_convert_x(const float* __restrict__ x, unsigned short* __restrict__ xb) {
  int i = (blockIdx.x * 256 + threadIdx.x) * 4;
  float4 v = *reinterpret_cast<const float4*>(x + i);
  ushort4 h;
  h.x = f2b(v.x); h.y = f2b(v.y); h.z = f2b(v.z); h.w = f2b(v.w);
  *reinterpret_cast<ushort4*>(xb + i) = h;
}

// ---------------------------------------------------------------- k2: qkv GEMM, 128x64 tile, dbuf, XCD remap (384 blocks)
__launch_bounds__(256, 2)
__global__ void k_qkv_gemm(const unsigned short* __restrict__ xb, const unsigned short* __restrict__ wT,
                           const float* __restrict__ bqkv,
                           unsigned short* __restrict__ Qb, unsigned short* __restrict__ Kb,
                           unsigned short* __restrict__ Vb) {
  const int hb = blockIdx.x;              // 0..383
  const int xcd = hb & 7, jj = hb >> 3;   // jj 0..47
  const int tau = xcd * 48 + jj;          // XCD x: bm in [8x, 8x+8)
  const int bn = tau % 6, bm = tau / 6;
  const int tid = threadIdx.x;
  const int lane = tid & 63, w = tid >> 6;
  const int l15 = lane & 15, g = lane >> 4;
  const int wm = (w >> 1) * 64, wn = (w & 1) * 32;
  const int row0 = bm * 128, col0 = bn * 64;

  __shared__ __align__(16) char Ash[2][16384];   // [128][64] bf16, swz
  __shared__ __align__(16) char Bsh[2][8192];    // [64][64] bf16, swz

  f32x4 acc[4][2] = {};

#define QKV_STAGE(k0, buf)                                                          \
  {                                                                                 \
    _Pragma("unroll")                                                               \
    for (int j2 = 0; j2 < 4; ++j2) {                                                \
      int idx = j2 * 256 + tid;                                                     \
      int r = idx >> 3, gg = idx & 7, sgg = gg ^ (r & 7);                           \
      GLOAD16(xb + (size_t)(row0 + r) * DIN + (k0) + sgg * 8, Ash[buf] + idx * 16); \
    }                                                                               \
    _Pragma("unroll")                                                               \
    for (int j2 = 0; j2 < 2; ++j2) {                                                \
      int idx = j2 * 256 + tid;                                                     \
      int r = idx >> 3, gg = idx & 7, sgg = gg ^ (r & 7);                           \
      GLOAD16(wT + (size_t)(col0 + r) * DIN + (k0) + sgg * 8, Bsh[buf] + idx * 16); \
    }                                                                               \
  }

  QKV_STAGE(0, 0);
  __syncthreads();
  int cur = 0;
  for (int k0 = 0; k0 < DIN; k0 += 64) {
    if (k0 + 64 < DIN) QKV_STAGE(k0 + 64, cur ^ 1);
#pragma unroll
    for (int ksl = 0; ksl < 2; ++ksl) {
      bf16x8 af[4], bfr[2];
#pragma unroll
      for (int i = 0; i < 4; ++i) {
        int r = wm + i * 16 + l15;
        int ba = r * 128 + ksl * 64 + g * 16;
        af[i] = *reinterpret_cast<bf16x8*>(Ash[cur] + (ba ^ ((r & 7) << 4)));
      }
#pragma unroll
      for (int jn = 0; jn < 2; ++jn) {
        int n = wn + jn * 16 + l15;
        int bb = n * 128 + ksl * 64 + g * 16;
        bfr[jn] = *reinterpret_cast<bf16x8*>(Bsh[cur] + (bb ^ ((n & 7) << 4)));
      }
#pragma unroll
      for (int i = 0; i < 4; ++i)
#pragma unroll
        for (int jn = 0; jn < 2; ++jn)
          acc[i][jn] = MFMA16(af[i], bfr[jn], acc[i][jn]);
    }
    __syncthreads();
    cur ^= 1;
  }

  const int which = col0 >> 7;            // 0/1/2 -> Q/K/V
  const int inner = col0 & 127;
  unsigned short* outb = (which == 0) ? Qb : (which == 1 ? Kb : Vb);
#pragma unroll
  for (int i = 0; i < 4; ++i)
#pragma unroll
    for (int jn = 0; jn < 2; ++jn)
#pragma unroll
      for (int r = 0; r < 4; ++r) {
        int grow = row0 + wm + i * 16 + g * 4 + r;
        int lcol = wn + jn * 16 + l15;               // 0..63
        float vv = acc[i][jn][r] + bqkv[col0 + lcol];
        outb[(size_t)grow * DH + inner + lcol] = f2b(vv);
      }
}

// ---------------------------------------------------------------- k3: V [8192][128] -> V^T [128][8192]
__global__ void k_transpose_v(const unsigned short* __restrict__ V, unsigned short* __restrict__ VT) {
  __shared__ __align__(16) unsigned short t[64 * 128];
  const int b = blockIdx.x;
  const int tid = threadIdx.x;
  const int kv0 = b * 64;
#pragma unroll
  for (int j = 0; j < 4; ++j) {
    int c = j * 256 + tid;
    int r = c >> 4, cc = (c & 15) * 8;
    uint4 v = *reinterpret_cast<const uint4*>(V + (size_t)(kv0 + r) * DH + cc);
    int col = (cc + ((r >> 3) & 7) * 8) & 127;
    *reinterpret_cast<uint4*>(&t[r * 128 + col]) = v;
  }
  __syncthreads();
#pragma unroll
  for (int j = 0; j < 4; ++j) {
    int c = j * 256 + tid;
    int d = c >> 3, kk = (c & 7) * 8;
    unsigned short tmp[8];
#pragma unroll
    for (int e = 0; e < 8; ++e) {
      int r = kk + e;
      int col = (d + ((r >> 3) & 7) * 8) & 127;
      tmp[e] = t[r * 128 + col];
    }
    *reinterpret_cast<uint4*>(VT + (size_t)d * NROWS + kv0 + kk) = *reinterpret_cast<uint4*>(tmp);
  }
}

// ---------------------------------------------------------------- k4: causal flash == round-7 structure (67us) + bf16 partials + setprio
// 4 waves x 32q (2 subtiles), swapped MFMA (S^T/O^T), per-lane softmax, dbuf K/V via global_load_lds.
// launch_bounds(256,2): never raise min-waves (r3/r5: allocator drops a VGPR tier and spills).
// Do NOT single-buffer the staging (r8: write phase lands on critical path, +50%).
__launch_bounds__(256, 2)
__global__ void k_flash(const unsigned short* __restrict__ Q, const unsigned short* __restrict__ Kg,
                        const unsigned short* __restrict__ VT,
                        unsigned short* __restrict__ Opart, float* __restrict__ MLpart, int LQ) {
  const int ci = blockIdx.x;
  const int t = (int)(gridDim.y - 1) - (int)blockIdx.y;   // heavy tiles first
  const int Jq = 1 << LQ;                                 // chunk = Jq*128 kv
  if (ci * Jq > t) return;
  const int qb = t << 7;
  const int ks = ci * (Jq << 7);
  const int ke = min(ks + (Jq << 7), qb + 128);
  const int nsteps = (ke - ks) >> 6;

  const int a = t >> LQ, b = t & (Jq - 1);
  const int slot = t + ((Jq * a * (a - 1)) >> 1) + a * b + ci;

  const int tid = threadIdx.x;
  const int lane = tid & 63, w = tid >> 6;
  const int l15 = lane & 15, g = lane >> 4;

  __shared__ __align__(16) char Ksh[2][16384];   // K [64][128] bf16, swz
  __shared__ __align__(16) char Vsh[2][16384];   // V^T [128][64] bf16, swz
  __shared__ __align__(16) char Psh[4][4096];    // per-wave P [32 q][64 k] bf16, swz

  const int qr0 = qb + w * 16 + l15;             // subtile-0 q row
  const int qr1 = qr0 + 64;                      // subtile-1 q row
  bf16x8 qf0[4], qf1[4];
#pragma unroll
  for (int d = 0; d < 4; ++d) {
    qf0[d] = *reinterpret_cast<const bf16x8*>(Q + (size_t)qr0 * DH + d * 32 + g * 8);
    qf1[d] = *reinterpret_cast<const bf16x8*>(Q + (size_t)qr1 * DH + d * 32 + g * 8);
  }

  f32x4 acco0[8] = {}, acco1[8] = {};
  float m0 = -1e30f, l0 = 0.f, m1 = -1e30f, l1 = 0.f;
  const float c2 = 0.08838834764831843f * 1.4426950408889634f;   // scale * log2(e)

#define FL_STAGE(kv0, buf)                                                            \
  {                                                                                   \
    _Pragma("unroll")                                                                 \
    for (int j2 = 0; j2 < 4; ++j2) {                                                  \
      int idx = j2 * 256 + tid;                                                       \
      int r = idx >> 4, gg = idx & 15, sgg = gg ^ (r & 7);                            \
      GLOAD16(Kg + (size_t)((kv0) + r) * DH + sgg * 8, Ksh[buf] + idx * 16);          \
    }                                                                                 \
    _Pragma("unroll")                                                                 \
    for (int j2 = 0; j2 < 4; ++j2) {                                                  \
      int idx = j2 * 256 + tid;                                                       \
      int d = idx >> 3, gg = idx & 7, sgg = gg ^ (d & 7);                             \
      GLOAD16(VT + (size_t)d * NROWS + (kv0) + sgg * 8, Vsh[buf] + idx * 16);         \
    }                                                                                 \
  }

  char* Pw = Psh[w];

  FL_STAGE(ks, 0);
  __syncthreads();
  int cur = 0;

  for (int s = 0; s < nsteps; ++s) {
    const int kv0 = ks + (s << 6);
    if (s + 1 < nsteps) FL_STAGE(kv0 + 64, cur ^ 1);
    const bool act0 = (kv0 < qb + 64);

    // QK^T (S^T): each K fragment read once, feeds both subtiles
    f32x4 accs0[4] = {}, accs1[4] = {};
    __builtin_amdgcn_s_setprio(1);
    if (act0) {
#pragma unroll
      for (int jc = 0; jc < 4; ++jc)
#pragma unroll
        for (int d = 0; d < 4; ++d) {
          int r = jc * 16 + l15;
          int byte = r * 256 + d * 64 + g * 16; byte ^= (r & 7) << 4;
          bf16x8 kf = *reinterpret_cast<bf16x8*>(Ksh[cur] + byte);
          accs1[jc] = MFMA16(kf, qf1[d], accs1[jc]);
          accs0[jc] = MFMA16(kf, qf0[d], accs0[jc]);
        }
    } else {
#pragma unroll
      for (int jc = 0; jc < 4; ++jc)
#pragma unroll
        for (int d = 0; d < 4; ++d) {
          int r = jc * 16 + l15;
          int byte = r * 256 + d * 64 + g * 16; byte ^= (r & 7) << 4;
          bf16x8 kf = *reinterpret_cast<bf16x8*>(Ksh[cur] + byte);
          accs1[jc] = MFMA16(kf, qf1[d], accs1[jc]);
        }
    }
    __builtin_amdgcn_s_setprio(0);

#define SOFTMAX_PW(ACCS, ACCO, M, L, QROW, ROWBASE)                                   \
    {                                                                                 \
      float p[4][4];                                                                  \
      float mx = -3e38f;                                                              \
      _Pragma("unroll")                                                               \
      for (int jc = 0; jc < 4; ++jc)                                                  \
        _Pragma("unroll")                                                             \
        for (int r = 0; r < 4; ++r) {                                                 \
          float sv = ACCS[jc][r] * c2;                                                \
          int kk = kv0 + jc * 16 + (g << 2) + r;                                      \
          sv = (kk <= (QROW)) ? sv : -3e38f;                                          \
          p[jc][r] = sv;                                                              \
          mx = fmaxf(mx, sv);                                                         \
        }                                                                             \
      mx = fmaxf(mx, __shfl_xor(mx, 16));                                             \
      mx = fmaxf(mx, __shfl_xor(mx, 32));                                             \
      float mnew = fmaxf(M, mx);                                                      \
      float fac = EXP2F(M - mnew);                                                    \
      float ps = 0.f;                                                                 \
      _Pragma("unroll")                                                               \
      for (int jc = 0; jc < 4; ++jc)                                                  \
        _Pragma("unroll")                                                             \
        for (int r = 0; r < 4; ++r) {                                                 \
          float e = EXP2F(p[jc][r] - mnew);                                           \
          p[jc][r] = e; ps += e;                                                      \
        }                                                                             \
      ps += __shfl_xor(ps, 16);                                                       \
      ps += __shfl_xor(ps, 32);                                                       \
      L = L * fac + ps;                                                               \
      M = mnew;                                                                       \
      _Pragma("unroll")                                                               \
      for (int dc = 0; dc < 8; ++dc)                                                  \
        _Pragma("unroll")                                                             \
        for (int r = 0; r < 4; ++r) ACCO[dc][r] *= fac;                               \
      int rq = (ROWBASE) + l15;                                                       \
      _Pragma("unroll")                                                               \
      for (int jc = 0; jc < 4; ++jc) {                                                \
        ushort4 pb;                                                                   \
        pb.x = f2b(p[jc][0]); pb.y = f2b(p[jc][1]);                                   \
        pb.z = f2b(p[jc][2]); pb.w = f2b(p[jc][3]);                                   \
        int byte = rq * 128 + jc * 32 + g * 8; byte ^= (rq & 7) << 4;                 \
        *reinterpret_cast<ushort4*>(Pw + byte) = pb;                                  \
      }                                                                               \
    }

    if (act0) SOFTMAX_PW(accs0, acco0, m0, l0, qr0, 0);
    SOFTMAX_PW(accs1, acco1, m1, l1, qr1, 16);
    __asm__ volatile("s_waitcnt lgkmcnt(0)" ::: "memory");
    __builtin_amdgcn_sched_barrier(0);

    // PV (O^T): each V fragment read once, feeds both subtiles
    bf16x8 pf1[2];
#pragma unroll
    for (int ks2 = 0; ks2 < 2; ++ks2) {
      int rq = 16 + l15;
      int byte = rq * 128 + ks2 * 64 + g * 16; byte ^= (rq & 7) << 4;
      pf1[ks2] = *reinterpret_cast<bf16x8*>(Pw + byte);
    }
    __builtin_amdgcn_s_setprio(1);
    if (act0) {
      bf16x8 pf0[2];
#pragma unroll
      for (int ks2 = 0; ks2 < 2; ++ks2) {
        int byte = l15 * 128 + ks2 * 64 + g * 16; byte ^= (l15 & 7) << 4;
        pf0[ks2] = *reinterpret_cast<bf16x8*>(Pw + byte);
      }
#pragma unroll
      for (int dc = 0; dc < 8; ++dc) {
        int vr = dc * 16 + l15;
        int b0 = vr * 128 + g * 16; b0 ^= (vr & 7) << 4;
        bf16x8 vf0 = *reinterpret_cast<bf16x8*>(Vsh[cur] + b0);
        bf16x8 vf1 = *reinterpret_cast<bf16x8*>(Vsh[cur] + (b0 ^ 64));
        acco1[dc] = MFMA16(vf0, pf1[0], acco1[dc]);
        acco1[dc] = MFMA16(vf1, pf1[1], acco1[dc]);
        acco0[dc] = MFMA16(vf0, pf0[0], acco0[dc]);
        acco0[dc] = MFMA16(vf1, pf0[1], acco0[dc]);
      }
    } else {
#pragma unroll
      for (int dc = 0; dc < 8; ++dc) {
        int vr = dc * 16 + l15;
        int b0 = vr * 128 + g * 16; b0 ^= (vr & 7) << 4;
        bf16x8 vf0 = *reinterpret_cast<bf16x8*>(Vsh[cur] + b0);
        bf16x8 vf1 = *reinterpret_cast<bf16x8*>(Vsh[cur] + (b0 ^ 64));
        acco1[dc] = MFMA16(vf0, pf1[0], acco1[dc]);
        acco1[dc] = MFMA16(vf1, pf1[1], acco1[dc]);
      }
    }
    __builtin_amdgcn_s_setprio(0);
    __syncthreads();
    cur ^= 1;
  }

  // epilogue: bf16 partials (validated r8: absmax unchanged)
  const size_t r0 = (size_t)slot * 128 + w * 16 + l15;
  const size_t r1 = r0 + 64;
#pragma unroll
  for (int dc = 0; dc < 8; ++dc) {
    ushort4 o0, o1;
    o0.x = f2b(acco0[dc][0]); o0.y = f2b(acco0[dc][1]);
    o0.z = f2b(acco0[dc][2]); o0.w = f2b(acco0[dc][3]);
    o1.x = f2b(acco1[dc][0]); o1.y = f2b(acco1[dc][1]);
    o1.z = f2b(acco1[dc][2]); o1.w = f2b(acco1[dc][3]);
    *reinterpret_cast<ushort4*>(Opart + r0 * DH + dc * 16 + (g << 2)) = o0;
    *reinterpret_cast<ushort4*>(Opart + r1 * DH + dc * 16 + (g << 2)) = o1;
  }
  if (g == 0) {
    MLpart[r0 * 2 + 0] = m0;
    MLpart[r0 * 2 + 1] = l0;
    MLpart[r1 * 2 + 0] = m1;
    MLpart[r1 * 2 + 1] = l1;
  }
}

// ---------------------------------------------------------------- k5: merge chunk partials (bf16) -> O bf16
__global__ void k_merge(const unsigned short* __restrict__ Opart, const float* __restrict__ MLpart,
                        unsigned short* __restrict__ O, int LQ) {
  int tg = blockIdx.x * 256 + threadIdx.x;     // over 8192*32
  int row = tg >> 5, d4 = (tg & 31) * 4;
  int t = row >> 7;                            // 128-row q tiles
  int Jq = 1 << LQ;
  int a = t >> LQ, b = t & (Jq - 1);
  int base = t + ((Jq * a * (a - 1)) >> 1) + a * b;
  int nc = a + 1;
  int rowin = row & 127;
  float M = -3e38f;
  for (int i = 0; i < nc; ++i) M = fmaxf(M, MLpart[((size_t)(base + i) * 128 + rowin) * 2]);
  float L = 0.f;
  f32x4 acc = {};
  for (int i = 0; i < nc; ++i) {
    size_t sr = (size_t)(base + i) * 128 + rowin;
    float mi = MLpart[sr * 2];
    float li = MLpart[sr * 2 + 1];
    float wg = EXP2F(mi - M);
    L += li * wg;
    ushort4 o = *reinterpret_cast<const ushort4*>(Opart + sr * DH + d4);
    acc[0] += wg * b2f(o.x); acc[1] += wg * b2f(o.y);
    acc[2] += wg * b2f(o.z); acc[3] += wg * b2f(o.w);
  }
  float inv = 1.f / L;
  ushort4 hv;
  hv.x = f2b(acc[0] * inv); hv.y = f2b(acc[1] * inv);
  hv.z = f2b(acc[2] * inv); hv.w = f2b(acc[3] * inv);
  *reinterpret_cast<ushort4*>(O + (size_t)row * DH + d4) = hv;
}

// ---------------------------------------------------------------- k6: out GEMM, 128x128 dbuf (512 blocks), XCD remap
__launch_bounds__(256, 2)
__global__ void k_out_gemm(const unsigned short* __restrict__ O, const unsigned short* __restrict__ wT,
                           const float* __restrict__ bout, float* __restrict__ out) {
  const int hb = blockIdx.x;               // 0..511
  const int xcd = hb & 7, jj = hb >> 3;    // jj 0..63
  const int tau = xcd * 64 + jj;           // XCD x: bm in [8x, 8x+8)
  const int bn = tau & 7, bm = tau >> 3;
  const int tid = threadIdx.x;
  const int lane = tid & 63, w = tid >> 6;
  const int l15 = lane & 15, g = lane >> 4;
  const int wm = (w >> 1) * 64, wn = (w & 1) * 64;
  const int row0 = bm * 128, col0 = bn * 128;

  __shared__ __align__(16) char Ash[2][16384];   // [128][64] bf16, swz
  __shared__ __align__(16) char Bsh[2][16384];

  f32x4 acc[4][4] = {};

#define OUT_STAGE(k0, buf)                                                          \
  {                                                                                 \
    _Pragma("unroll")                                                               \
    for (int j2 = 0; j2 < 4; ++j2) {                                                \
      int idx = j2 * 256 + tid;                                                     \
      int r = idx >> 3, gg = idx & 7, sgg = gg ^ (r & 7);                           \
      GLOAD16(O + (size_t)(row0 + r) * DH + (k0) + sgg * 8, Ash[buf] + idx * 16);   \
      GLOAD16(wT + (size_t)(col0 + r) * DH + (k0) + sgg * 8, Bsh[buf] + idx * 16);  \
    }                                                                               \
  }

  OUT_STAGE(0, 0);
  __syncthreads();
  int cur = 0;
  for (int k0 = 0; k0 < DH; k0 += 64) {
    if (k0 + 64 < DH) OUT_STAGE(k0 + 64, cur ^ 1);
#pragma unroll
    for (int ksl = 0; ksl < 2; ++ksl) {
      bf16x8 af[4], bfr[4];
#pragma unroll
      for (int i = 0; i < 4; ++i) {
        int r = wm + i * 16 + l15;
        int ba = r * 128 + ksl * 64 + g * 16;
        af[i] = *reinterpret_cast<bf16x8*>(Ash[cur] + (ba ^ ((r & 7) << 4)));
        int n = wn + i * 16 + l15;
        int bb = n * 128 + ksl * 64 + g * 16;
        bfr[i] = *reinterpret_cast<bf16x8*>(Bsh[cur] + (bb ^ ((n & 7) << 4)));
      }
#pragma unroll
      for (int i = 0; i < 4; ++i)
#pragma unroll
        for (int jn = 0; jn < 4; ++jn)
          acc[i][jn] = MFMA16(af[i], bfr[jn], acc[i][jn]);
    }
    __syncthreads();
    cur ^= 1;
  }

#pragma unroll
  for (int i = 0; i < 4; ++i)
#pragma unroll
    for (int jn = 0; jn < 4; ++jn)
#pragma unroll
      for (int r = 0; r < 4; ++r) {
        int grow = row0 + wm + i * 16 + g * 4 + r;
        int gcol = col0 + wn + jn * 16 + l15;
        out[(size_t)grow * DOUT + gcol] = acc[i][jn][r] + bout[gcol];
      }
}

// ---------------------------------------------------------------- launch
extern "C" void kernel_launch(void* const* d_in, const int* in_sizes, int n_in,
                              void* d_out, int out_size, void* d_ws, size_t ws_size,
                              hipStream_t stream) {
  const float* x    = (const float*)d_in[0];
  const float* wqkv = (const float*)d_in[1];
  const float* bqkv = (const float*)d_in[2];
  const float* wout = (const float*)d_in[3];
  const float* bout = (const float*)d_in[4];
  float* out = (float*)d_out;

  // adaptive KV-chunk: 64 q-tiles of 128 rows; chunk = Jq*128 kv. bf16 partials.
  // LQ=2 proven best (r7); LQ=1 regressed (r8: doubled prologue + K/V re-read).
  size_t fixed = 786432 + 262144 + (size_t)NROWS * DIN * 2 + (size_t)5 * NROWS * DH * 2;
  int LQ = 2;
  size_t slots = 0;
  for (; LQ <= 6; ++LQ) {
    int Jq = 1 << LQ, A = 64 / Jq;
    slots = (size_t)Jq * A * (A + 1) / 2;
    size_t need = fixed + slots * ((size_t)128 * DH * 2 + 128 * 8);
    if (need <= ws_size || LQ == 6) break;
  }

  char* ws = (char*)d_ws;
  size_t off = 0;
  unsigned short* wqkvT = (unsigned short*)(ws + off); off += (size_t)384 * 1024 * 2;
  unsigned short* woutT = (unsigned short*)(ws + off); off += (size_t)1024 * 128 * 2;
  unsigned short* xb  = (unsigned short*)(ws + off); off += (size_t)NROWS * DIN * 2;
  unsigned short* Qb  = (unsigned short*)(ws + off); off += (size_t)NROWS * DH * 2;
  unsigned short* Kb  = (unsigned short*)(ws + off); off += (size_t)NROWS * DH * 2;
  unsigned short* Vb  = (unsigned short*)(ws + off); off += (size_t)NROWS * DH * 2;
  unsigned short* VTb = (unsigned short*)(ws + off); off += (size_t)NROWS * DH * 2;
  unsigned short* Ob  = (unsigned short*)(ws + off); off += (size_t)NROWS * DH * 2;
  unsigned short* Opart = (unsigned short*)(ws + off); off += slots * (size_t)128 * DH * 2;
  float* MLpart = (float*)(ws + off); off += slots * (size_t)128 * 8;

  k_convert_w<<<128, 256, 0, stream>>>(wqkv, wout, wqkvT, woutT);
  k_convert_x<<<(NROWS * DIN) / 1024, 256, 0, stream>>>(x, xb);
  k_qkv_gemm<<<384, 256, 0, stream>>>(xb, wqkvT, bqkv, Qb, Kb, Vb);
  k_transpose_v<<<128, 256, 0, stream>>>(Vb, VTb);
  k_flash<<<dim3(64 >> LQ, 64), 256, 0, stream>>>(Qb, Kb, VTb, Opart, MLpart, LQ);
  k_merge<<<(NROWS * 32) / 256, 256, 0, stream>>>(Opart, MLpart, Ob, LQ);
  k_out_gemm<<<512, 256, 0, stream>>>(Ob, woutT, bout, out);
}

// Round 10
// 110.761 us; speedup vs baseline: 1.4328x; 1.0429x over previous
//
#include <hip/hip_runtime.h>
#include <stdint.h>

typedef __attribute__((ext_vector_type(4))) float f32x4;
typedef __attribute__((ext_vector_type(8))) __bf16 bf16x8;

#define MFMA16(a, b, c) __builtin_amdgcn_mfma_f32_16x16x32_bf16(a, b, c, 0, 0, 0)
#define GLOAD16(g, l)                                                              \
  __builtin_amdgcn_global_load_lds(                                                \
      (const __attribute__((address_space(1))) unsigned int*)(g),                  \
      (__attribute__((address_space(3))) unsigned int*)(l), 16, 0, 0)
#define EXP2F(x) __builtin_amdgcn_exp2f(x)

static __device__ __forceinline__ unsigned short f2b(float f) {
  unsigned int u = __float_as_uint(f);
  u += 0x7fff + ((u >> 16) & 1);
  return (unsigned short)(u >> 16);
}
static __device__ __forceinline__ float b2f(unsigned short h) {
  unsigned int u = ((unsigned int)h) << 16;
  return __uint_as_float(u);
}
// HW packed f32->bf16 (RNE), 2 values / instruction (T12 primitive)
static __device__ __forceinline__ unsigned int cvt_pk_bf16(float a, float b) {
  unsigned int r;
  asm("v_cvt_pk_bf16_f32 %0, %1, %2" : "=v"(r) : "v"(a), "v"(b));
  return r;
}

#define NROWS 8192
#define DIN   1024
#define DH    128
#define DOUT  1024

// ---------------------------------------------------------------- k1: x -> bf16 AND weights -> bf16 transposed (merged)
__global__ void k_convert(const float* __restrict__ x, const float* __restrict__ wqkv,
                          const float* __restrict__ wout,
                          unsigned short* __restrict__ xb,
                          unsigned short* __restrict__ wqkvT, unsigned short* __restrict__ woutT) {
  const int bid = blockIdx.x;
  const int tid = threadIdx.x;
  if (bid < 8192) {                     // x -> bf16 (33.5 MB read)
    int i = (bid * 256 + tid) * 4;
    float4 v = *reinterpret_cast<const float4*>(x + i);
    ushort4 h;
    h.x = f2b(v.x); h.y = f2b(v.y); h.z = f2b(v.z); h.w = f2b(v.w);
    *reinterpret_cast<ushort4*>(xb + i) = h;
    return;
  }
  __shared__ float t[64][65];
  const int wb = bid - 8192;            // 0..127
  const float* src;
  unsigned short* dst;
  int k0, n0, sstride, dstride;
  if (wb < 96) {                        // wqkv [1024][384] -> wqkvT [384][1024]
    int kt = wb / 6, nt = wb % 6;
    k0 = kt * 64; n0 = nt * 64;
    src = wqkv; sstride = 384; dst = wqkvT; dstride = 1024;
  } else {                              // wout [128][1024] -> woutT [1024][128]
    int b2 = wb - 96;
    int kt = b2 & 1, nt = b2 >> 1;
    k0 = kt * 64; n0 = nt * 64;
    src = wout; sstride = 1024; dst = woutT; dstride = 128;
  }
  const int r = tid >> 4, c4 = (tid & 15) * 4;
#pragma unroll
  for (int j = 0; j < 4; ++j) {
    int rr = r + j * 16;
    float4 v = *reinterpret_cast<const float4*>(src + (size_t)(k0 + rr) * sstride + n0 + c4);
    t[rr][c4 + 0] = v.x; t[rr][c4 + 1] = v.y; t[rr][c4 + 2] = v.z; t[rr][c4 + 3] = v.w;
  }
  __syncthreads();
#pragma unroll
  for (int j = 0; j < 4; ++j) {
    int rn = r + j * 16;
    ushort4 h;
    h.x = f2b(t[c4 + 0][rn]); h.y = f2b(t[c4 + 1][rn]);
    h.z = f2b(t[c4 + 2][rn]); h.w = f2b(t[c4 + 3][rn]);
    *reinterpret_cast<ushort4*>(dst + (size_t)(n0 + rn) * dstride + k0 + c4) = h;
  }
}

// ---------------------------------------------------------------- k2: qkv GEMM, 128x64 tile, dbuf, XCD remap (384 blocks)
__launch_bounds__(256, 2)
__global__ void k_qkv_gemm(const unsigned short* __restrict__ xb, const unsigned short* __restrict__ wT,
                           const float* __restrict__ bqkv,
                           unsigned short* __restrict__ Qb, unsigned short* __restrict__ Kb,
                           unsigned short* __restrict__ Vb) {
  const int hb = blockIdx.x;              // 0..383
  const int xcd = hb & 7, jj = hb >> 3;   // jj 0..47
  const int tau = xcd * 48 + jj;          // XCD x: bm in [8x, 8x+8)
  const int bn = tau % 6, bm = tau / 6;
  const int tid = threadIdx.x;
  const int lane = tid & 63, w = tid >> 6;
  const int l15 = lane & 15, g = lane >> 4;
  const int wm = (w >> 1) * 64, wn = (w & 1) * 32;
  const int row0 = bm * 128, col0 = bn * 64;

  __shared__ __align__(16) char Ash[2][16384];   // [128][64] bf16, swz
  __shared__ __align__(16) char Bsh[2][8192];    // [64][64] bf16, swz

  f32x4 acc[4][2] = {};

#define QKV_STAGE(k0, buf)                                                          \
  {                                                                                 \
    _Pragma("unroll")                                                               \
    for (int j2 = 0; j2 < 4; ++j2) {                                                \
      int idx = j2 * 256 + tid;                                                     \
      int r = idx >> 3, gg = idx & 7, sgg = gg ^ (r & 7);                           \
      GLOAD16(xb + (size_t)(row0 + r) * DIN + (k0) + sgg * 8, Ash[buf] + idx * 16); \
    }                                                                               \
    _Pragma("unroll")                                                               \
    for (int j2 = 0; j2 < 2; ++j2) {                                                \
      int idx = j2 * 256 + tid;                                                     \
      int r = idx >> 3, gg = idx & 7, sgg = gg ^ (r & 7);                           \
      GLOAD16(wT + (size_t)(col0 + r) * DIN + (k0) + sgg * 8, Bsh[buf] + idx * 16); \
    }                                                                               \
  }

  QKV_STAGE(0, 0);
  __syncthreads();
  int cur = 0;
  for (int k0 = 0; k0 < DIN; k0 += 64) {
    if (k0 + 64 < DIN) QKV_STAGE(k0 + 64, cur ^ 1);
#pragma unroll
    for (int ksl = 0; ksl < 2; ++ksl) {
      bf16x8 af[4], bfr[2];
#pragma unroll
      for (int i = 0; i < 4; ++i) {
        int r = wm + i * 16 + l15;
        int ba = r * 128 + ksl * 64 + g * 16;
        af[i] = *reinterpret_cast<bf16x8*>(Ash[cur] + (ba ^ ((r & 7) << 4)));
      }
#pragma unroll
      for (int jn = 0; jn < 2; ++jn) {
        int n = wn + jn * 16 + l15;
        int bb = n * 128 + ksl * 64 + g * 16;
        bfr[jn] = *reinterpret_cast<bf16x8*>(Bsh[cur] + (bb ^ ((n & 7) << 4)));
      }
#pragma unroll
      for (int i = 0; i < 4; ++i)
#pragma unroll
        for (int jn = 0; jn < 2; ++jn)
          acc[i][jn] = MFMA16(af[i], bfr[jn], acc[i][jn]);
    }
    __syncthreads();
    cur ^= 1;
  }

  const int which = col0 >> 7;            // 0/1/2 -> Q/K/V
  const int inner = col0 & 127;
  unsigned short* outb = (which == 0) ? Qb : (which == 1 ? Kb : Vb);
#pragma unroll
  for (int i = 0; i < 4; ++i)
#pragma unroll
    for (int jn = 0; jn < 2; ++jn)
#pragma unroll
      for (int r = 0; r < 4; ++r) {
        int grow = row0 + wm + i * 16 + g * 4 + r;
        int lcol = wn + jn * 16 + l15;               // 0..63
        float vv = acc[i][jn][r] + bqkv[col0 + lcol];
        outb[(size_t)grow * DH + inner + lcol] = f2b(vv);
      }
}

// ---------------------------------------------------------------- k3: V [8192][128] -> V^T [128][8192]
__global__ void k_transpose_v(const unsigned short* __restrict__ V, unsigned short* __restrict__ VT) {
  __shared__ __align__(16) unsigned short t[64 * 128];
  const int b = blockIdx.x;
  const int tid = threadIdx.x;
  const int kv0 = b * 64;
#pragma unroll
  for (int j = 0; j < 4; ++j) {
    int c = j * 256 + tid;
    int r = c >> 4, cc = (c & 15) * 8;
    uint4 v = *reinterpret_cast<const uint4*>(V + (size_t)(kv0 + r) * DH + cc);
    int col = (cc + ((r >> 3) & 7) * 8) & 127;
    *reinterpret_cast<uint4*>(&t[r * 128 + col]) = v;
  }
  __syncthreads();
#pragma unroll
  for (int j = 0; j < 4; ++j) {
    int c = j * 256 + tid;
    int d = c >> 3, kk = (c & 7) * 8;
    unsigned short tmp[8];
#pragma unroll
    for (int e = 0; e < 8; ++e) {
      int r = kk + e;
      int col = (d + ((r >> 3) & 7) * 8) & 127;
      tmp[e] = t[r * 128 + col];
    }
    *reinterpret_cast<uint4*>(VT + (size_t)d * NROWS + kv0 + kk) = *reinterpret_cast<uint4*>(tmp);
  }
}

// ---------------------------------------------------------------- k4: causal flash — r7 structure + chain surgery:
//  (a) no asm lgkmcnt wall (compiler-visible LDS deps -> fine-grained lgkmcnt, rule-18 N/A),
//  (b) v_cvt_pk_bf16_f32 for P pack (2 vals/instr, HW RNE),
//  (c) defer-max THR=8 (log2 domain): skip fac+acco-rescale when __all(mx <= M+8) — removes
//      rescale from softmax->PV chain; P bounded by 2^8, f32 l and bf16 P safe.
// launch_bounds(256,2): never raise min-waves (r3/r5). Dbuf staging (r8: single-buf +50%).
__launch_bounds__(256, 2)
__global__ void k_flash(const unsigned short* __restrict__ Q, const unsigned short* __restrict__ Kg,
                        const unsigned short* __restrict__ VT,
                        unsigned short* __restrict__ Opart, float* __restrict__ MLpart, int LQ) {
  const int ci = blockIdx.x;
  const int t = (int)(gridDim.y - 1) - (int)blockIdx.y;   // heavy tiles first
  const int Jq = 1 << LQ;                                 // chunk = Jq*128 kv
  if (ci * Jq > t) return;
  const int qb = t << 7;
  const int ks = ci * (Jq << 7);
  const int ke = min(ks + (Jq << 7), qb + 128);
  const int nsteps = (ke - ks) >> 6;

  const int a = t >> LQ, b = t & (Jq - 1);
  const int slot = t + ((Jq * a * (a - 1)) >> 1) + a * b + ci;

  const int tid = threadIdx.x;
  const int lane = tid & 63, w = tid >> 6;
  const int l15 = lane & 15, g = lane >> 4;

  __shared__ __align__(16) char Ksh[2][16384];   // K [64][128] bf16, swz
  __shared__ __align__(16) char Vsh[2][16384];   // V^T [128][64] bf16, swz
  __shared__ __align__(16) char Psh[4][4096];    // per-wave P [32 q][64 k] bf16, swz

  const int qr0 = qb + w * 16 + l15;             // subtile-0 q row
  const int qr1 = qr0 + 64;                      // subtile-1 q row
  bf16x8 qf0[4], qf1[4];
#pragma unroll
  for (int d = 0; d < 4; ++d) {
    qf0[d] = *reinterpret_cast<const bf16x8*>(Q + (size_t)qr0 * DH + d * 32 + g * 8);
    qf1[d] = *reinterpret_cast<const bf16x8*>(Q + (size_t)qr1 * DH + d * 32 + g * 8);
  }

  f32x4 acco0[8] = {}, acco1[8] = {};
  float m0 = -1e30f, l0 = 0.f, m1 = -1e30f, l1 = 0.f;
  const float c2 = 0.08838834764831843f * 1.4426950408889634f;   // scale * log2(e)

#define FL_STAGE(kv0, buf)                                                            \
  {                                                                                   \
    _Pragma("unroll")                                                                 \
    for (int j2 = 0; j2 < 4; ++j2) {                                                  \
      int idx = j2 * 256 + tid;                                                       \
      int r = idx >> 4, gg = idx & 15, sgg = gg ^ (r & 7);                            \
      GLOAD16(Kg + (size_t)((kv0) + r) * DH + sgg * 8, Ksh[buf] + idx * 16);          \
    }                                                                                 \
    _Pragma("unroll")                                                                 \
    for (int j2 = 0; j2 < 4; ++j2) {                                                  \
      int idx = j2 * 256 + tid;                                                       \
      int d = idx >> 3, gg = idx & 7, sgg = gg ^ (d & 7);                             \
      GLOAD16(VT + (size_t)d * NROWS + (kv0) + sgg * 8, Vsh[buf] + idx * 16);         \
    }                                                                                 \
  }

  char* Pw = Psh[w];

  FL_STAGE(ks, 0);
  __syncthreads();
  int cur = 0;

  for (int s = 0; s < nsteps; ++s) {
    const int kv0 = ks + (s << 6);
    if (s + 1 < nsteps) FL_STAGE(kv0 + 64, cur ^ 1);
    const bool act0 = (kv0 < qb + 64);

    // QK^T (S^T): each K fragment read once, feeds both subtiles
    f32x4 accs0[4] = {}, accs1[4] = {};
    __builtin_amdgcn_s_setprio(1);
    if (act0) {
#pragma unroll
      for (int jc = 0; jc < 4; ++jc)
#pragma unroll
        for (int d = 0; d < 4; ++d) {
          int r = jc * 16 + l15;
          int byte = r * 256 + d * 64 + g * 16; byte ^= (r & 7) << 4;
          bf16x8 kf = *reinterpret_cast<bf16x8*>(Ksh[cur] + byte);
          accs1[jc] = MFMA16(kf, qf1[d], accs1[jc]);
          accs0[jc] = MFMA16(kf, qf0[d], accs0[jc]);
        }
    } else {
#pragma unroll
      for (int jc = 0; jc < 4; ++jc)
#pragma unroll
        for (int d = 0; d < 4; ++d) {
          int r = jc * 16 + l15;
          int byte = r * 256 + d * 64 + g * 16; byte ^= (r & 7) << 4;
          bf16x8 kf = *reinterpret_cast<bf16x8*>(Ksh[cur] + byte);
          accs1[jc] = MFMA16(kf, qf1[d], accs1[jc]);
        }
    }
    __builtin_amdgcn_s_setprio(0);

    // softmax + deferred rescale + P-write per subtile (per-lane state; q = l15)
#define SOFTMAX_PW(ACCS, ACCO, M, L, QROW, ROWBASE)                                   \
    {                                                                                 \
      float p[4][4];                                                                  \
      float mx = -3e38f;                                                              \
      _Pragma("unroll")                                                               \
      for (int jc = 0; jc < 4; ++jc)                                                  \
        _Pragma("unroll")                                                             \
        for (int r = 0; r < 4; ++r) {                                                 \
          float sv = ACCS[jc][r] * c2;                                                \
          int kk = kv0 + jc * 16 + (g << 2) + r;                                      \
          sv = (kk <= (QROW)) ? sv : -3e38f;                                          \
          p[jc][r] = sv;                                                              \
          mx = fmaxf(mx, sv);                                                         \
        }                                                                             \
      mx = fmaxf(mx, __shfl_xor(mx, 16));                                             \
      mx = fmaxf(mx, __shfl_xor(mx, 32));                                             \
      if (!__all(mx <= M + 8.f)) {           /* defer-max: rescale only on growth */  \
        float mnew = fmaxf(M, mx);                                                    \
        float fac = EXP2F(M - mnew);                                                  \
        L *= fac;                                                                     \
        M = mnew;                                                                     \
        _Pragma("unroll")                                                             \
        for (int dc = 0; dc < 8; ++dc)                                                \
          _Pragma("unroll")                                                           \
          for (int r = 0; r < 4; ++r) ACCO[dc][r] *= fac;                             \
      }                                                                               \
      float ps = 0.f;                                                                 \
      _Pragma("unroll")                                                               \
      for (int jc = 0; jc < 4; ++jc)                                                  \
        _Pragma("unroll")                                                             \
        for (int r = 0; r < 4; ++r) {                                                 \
          float e = EXP2F(p[jc][r] - M);                                              \
          p[jc][r] = e; ps += e;                                                      \
        }                                                                             \
      ps += __shfl_xor(ps, 16);                                                       \
      ps += __shfl_xor(ps, 32);                                                       \
      L += ps;                                                                        \
      int rq = (ROWBASE) + l15;                                                       \
      _Pragma("unroll")                                                               \
      for (int jc = 0; jc < 4; ++jc) {                                                \
        uint2 pb;                                                                     \
        pb.x = cvt_pk_bf16(p[jc][0], p[jc][1]);                                       \
        pb.y = cvt_pk_bf16(p[jc][2], p[jc][3]);                                       \
        int byte = rq * 128 + jc * 32 + g * 8; byte ^= (rq & 7) << 4;                 \
        *reinterpret_cast<uint2*>(Pw + byte) = pb;                                    \
      }                                                                               \
    }

    if (act0) SOFTMAX_PW(accs0, acco0, m0, l0, qr0, 0);
    SOFTMAX_PW(accs1, acco1, m1, l1, qr1, 16);
    // (no asm wall: P write/read are same-wave, compiler inserts fine-grained lgkmcnt)

    // PV (O^T): each V fragment read once, feeds both subtiles
    bf16x8 pf1[2];
#pragma unroll
    for (int ks2 = 0; ks2 < 2; ++ks2) {
      int rq = 16 + l15;
      int byte = rq * 128 + ks2 * 64 + g * 16; byte ^= (rq & 7) << 4;
      pf1[ks2] = *reinterpret_cast<bf16x8*>(Pw + byte);
    }
    __builtin_amdgcn_s_setprio(1);
    if (act0) {
      bf16x8 pf0[2];
#pragma unroll
      for (int ks2 = 0; ks2 < 2; ++ks2) {
        int byte = l15 * 128 + ks2 * 64 + g * 16; byte ^= (l15 & 7) << 4;
        pf0[ks2] = *reinterpret_cast<bf16x8*>(Pw + byte);
      }
#pragma unroll
      for (int dc = 0; dc < 8; ++dc) {
        int vr = dc * 16 + l15;
        int b0 = vr * 128 + g * 16; b0 ^= (vr & 7) << 4;
        bf16x8 vf0 = *reinterpret_cast<bf16x8*>(Vsh[cur] + b0);
        bf16x8 vf1 = *reinterpret_cast<bf16x8*>(Vsh[cur] + (b0 ^ 64));
        acco1[dc] = MFMA16(vf0, pf1[0], acco1[dc]);
        acco1[dc] = MFMA16(vf1, pf1[1], acco1[dc]);
        acco0[dc] = MFMA16(vf0, pf0[0], acco0[dc]);
        acco0[dc] = MFMA16(vf1, pf0[1], acco0[dc]);
      }
    } else {
#pragma unroll
      for (int dc = 0; dc < 8; ++dc) {
        int vr = dc * 16 + l15;
        int b0 = vr * 128 + g * 16; b0 ^= (vr & 7) << 4;
        bf16x8 vf0 = *reinterpret_cast<bf16x8*>(Vsh[cur] + b0);
        bf16x8 vf1 = *reinterpret_cast<bf16x8*>(Vsh[cur] + (b0 ^ 64));
        acco1[dc] = MFMA16(vf0, pf1[0], acco1[dc]);
        acco1[dc] = MFMA16(vf1, pf1[1], acco1[dc]);
      }
    }
    __builtin_amdgcn_s_setprio(0);
    __syncthreads();
    cur ^= 1;
  }

  // epilogue: bf16 partials via cvt_pk
  const size_t r0 = (size_t)slot * 128 + w * 16 + l15;
  const size_t r1 = r0 + 64;
#pragma unroll
  for (int dc = 0; dc < 8; ++dc) {
    uint2 o0, o1;
    o0.x = cvt_pk_bf16(acco0[dc][0], acco0[dc][1]);
    o0.y = cvt_pk_bf16(acco0[dc][2], acco0[dc][3]);
    o1.x = cvt_pk_bf16(acco1[dc][0], acco1[dc][1]);
    o1.y = cvt_pk_bf16(acco1[dc][2], acco1[dc][3]);
    *reinterpret_cast<uint2*>(Opart + r0 * DH + dc * 16 + (g << 2)) = o0;
    *reinterpret_cast<uint2*>(Opart + r1 * DH + dc * 16 + (g << 2)) = o1;
  }
  if (g == 0) {
    MLpart[r0 * 2 + 0] = m0;
    MLpart[r0 * 2 + 1] = l0;
    MLpart[r1 * 2 + 0] = m1;
    MLpart[r1 * 2 + 1] = l1;
  }
}

// ---------------------------------------------------------------- k5: merge chunk partials (bf16) -> O bf16
__global__ void k_merge(const unsigned short* __restrict__ Opart, const float* __restrict__ MLpart,
                        unsigned short* __restrict__ O, int LQ) {
  int tg = blockIdx.x * 256 + threadIdx.x;     // over 8192*32
  int row = tg >> 5, d4 = (tg & 31) * 4;
  int t = row >> 7;                            // 128-row q tiles
  int Jq = 1 << LQ;
  int a = t >> LQ, b = t & (Jq - 1);
  int base = t + ((Jq * a * (a - 1)) >> 1) + a * b;
  int nc = a + 1;
  int rowin = row & 127;
  float M = -3e38f;
  for (int i = 0; i < nc; ++i) M = fmaxf(M, MLpart[((size_t)(base + i) * 128 + rowin) * 2]);
  float L = 0.f;
  f32x4 acc = {};
  for (int i = 0; i < nc; ++i) {
    size_t sr = (size_t)(base + i) * 128 + rowin;
    float mi = MLpart[sr * 2];
    float li = MLpart[sr * 2 + 1];
    float wg = EXP2F(mi - M);
    L += li * wg;
    ushort4 o = *reinterpret_cast<const ushort4*>(Opart + sr * DH + d4);
    acc[0] += wg * b2f(o.x); acc[1] += wg * b2f(o.y);
    acc[2] += wg * b2f(o.z); acc[3] += wg * b2f(o.w);
  }
  float inv = 1.f / L;
  uint2 hv;
  hv.x = cvt_pk_bf16(acc[0] * inv, acc[1] * inv);
  hv.y = cvt_pk_bf16(acc[2] * inv, acc[3] * inv);
  *reinterpret_cast<uint2*>(O + (size_t)row * DH + d4) = hv;
}

// ---------------------------------------------------------------- k6: out GEMM, 128x128 dbuf (512 blocks), XCD remap
__launch_bounds__(256, 2)
__global__ void k_out_gemm(const unsigned short* __restrict__ O, const unsigned short* __restrict__ wT,
                           const float* __restrict__ bout, float* __restrict__ out) {
  const int hb = blockIdx.x;               // 0..511
  const int xcd = hb & 7, jj = hb >> 3;    // jj 0..63
  const int tau = xcd * 64 + jj;           // XCD x: bm in [8x, 8x+8)
  const int bn = tau & 7, bm = tau >> 3;
  const int tid = threadIdx.x;
  const int lane = tid & 63, w = tid >> 6;
  const int l15 = lane & 15, g = lane >> 4;
  const int wm = (w >> 1) * 64, wn = (w & 1) * 64;
  const int row0 = bm * 128, col0 = bn * 128;

  __shared__ __align__(16) char Ash[2][16384];   // [128][64] bf16, swz
  __shared__ __align__(16) char Bsh[2][16384];

  f32x4 acc[4][4] = {};

#define OUT_STAGE(k0, buf)                                                          \
  {                                                                                 \
    _Pragma("unroll")                                                               \
    for (int j2 = 0; j2 < 4; ++j2) {                                                \
      int idx = j2 * 256 + tid;                                                     \
      int r = idx >> 3, gg = idx & 7, sgg = gg ^ (r & 7);                           \
      GLOAD16(O + (size_t)(row0 + r) * DH + (k0) + sgg * 8, Ash[buf] + idx * 16);   \
      GLOAD16(wT + (size_t)(col0 + r) * DH + (k0) + sgg * 8, Bsh[buf] + idx * 16);  \
    }                                                                               \
  }

  OUT_STAGE(0, 0);
  __syncthreads();
  int cur = 0;
  for (int k0 = 0; k0 < DH; k0 += 64) {
    if (k0 + 64 < DH) OUT_STAGE(k0 + 64, cur ^ 1);
#pragma unroll
    for (int ksl = 0; ksl < 2; ++ksl) {
      bf16x8 af[4], bfr[4];
#pragma unroll
      for (int i = 0; i < 4; ++i) {
        int r = wm + i * 16 + l15;
        int ba = r * 128 + ksl * 64 + g * 16;
        af[i] = *reinterpret_cast<bf16x8*>(Ash[cur] + (ba ^ ((r & 7) << 4)));
        int n = wn + i * 16 + l15;
        int bb = n * 128 + ksl * 64 + g * 16;
        bfr[i] = *reinterpret_cast<bf16x8*>(Bsh[cur] + (bb ^ ((n & 7) << 4)));
      }
#pragma unroll
      for (int i = 0; i < 4; ++i)
#pragma unroll
        for (int jn = 0; jn < 4; ++jn)
          acc[i][jn] = MFMA16(af[i], bfr[jn], acc[i][jn]);
    }
    __syncthreads();
    cur ^= 1;
  }

#pragma unroll
  for (int i = 0; i < 4; ++i)
#pragma unroll
    for (int jn = 0; jn < 4; ++jn)
#pragma unroll
      for (int r = 0; r < 4; ++r) {
        int grow = row0 + wm + i * 16 + g * 4 + r;
        int gcol = col0 + wn + jn * 16 + l15;
        out[(size_t)grow * DOUT + gcol] = acc[i][jn][r] + bout[gcol];
      }
}

// ---------------------------------------------------------------- launch
extern "C" void kernel_launch(void* const* d_in, const int* in_sizes, int n_in,
                              void* d_out, int out_size, void* d_ws, size_t ws_size,
                              hipStream_t stream) {
  const float* x    = (const float*)d_in[0];
  const float* wqkv = (const float*)d_in[1];
  const float* bqkv = (const float*)d_in[2];
  const float* wout = (const float*)d_in[3];
  const float* bout = (const float*)d_in[4];
  float* out = (float*)d_out;

  // adaptive KV-chunk: 64 q-tiles of 128 rows; chunk = Jq*128 kv. bf16 partials.
  // LQ=2 proven best (r7); LQ=1 regressed (r8).
  size_t fixed = 786432 + 262144 + (size_t)NROWS * DIN * 2 + (size_t)5 * NROWS * DH * 2;
  int LQ = 2;
  size_t slots = 0;
  for (; LQ <= 6; ++LQ) {
    int Jq = 1 << LQ, A = 64 / Jq;
    slots = (size_t)Jq * A * (A + 1) / 2;
    size_t need = fixed + slots * ((size_t)128 * DH * 2 + 128 * 8);
    if (need <= ws_size || LQ == 6) break;
  }

  char* ws = (char*)d_ws;
  size_t off = 0;
  unsigned short* wqkvT = (unsigned short*)(ws + off); off += (size_t)384 * 1024 * 2;
  unsigned short* woutT = (unsigned short*)(ws + off); off += (size_t)1024 * 128 * 2;
  unsigned short* xb  = (unsigned short*)(ws + off); off += (size_t)NROWS * DIN * 2;
  unsigned short* Qb  = (unsigned short*)(ws + off); off += (size_t)NROWS * DH * 2;
  unsigned short* Kb  = (unsigned short*)(ws + off); off += (size_t)NROWS * DH * 2;
  unsigned short* Vb  = (unsigned short*)(ws + off); off += (size_t)NROWS * DH * 2;
  unsigned short* VTb = (unsigned short*)(ws + off); off += (size_t)NROWS * DH * 2;
  unsigned short* Ob  = (unsigned short*)(ws + off); off += (size_t)NROWS * DH * 2;
  unsigned short* Opart = (unsigned short*)(ws + off); off += slots * (size_t)128 * DH * 2;
  float* MLpart = (float*)(ws + off); off += slots * (size_t)128 * 8;

  k_convert<<<8320, 256, 0, stream>>>(x, wqkv, wout, xb, wqkvT, woutT);
  k_qkv_gemm<<<384, 256, 0, stream>>>(xb, wqkvT, bqkv, Qb, Kb, Vb);
  k_transpose_v<<<128, 256, 0, stream>>>(Vb, VTb);
  k_flash<<<dim3(64 >> LQ, 64), 256, 0, stream>>>(Qb, Kb, VTb, Opart, MLpart, LQ);
  k_merge<<<(NROWS * 32) / 256, 256, 0, stream>>>(Opart, MLpart, Ob, LQ);
  k_out_gemm<<<512, 256, 0, stream>>>(Ob, woutT, bout, out);
}